// Round 2
// baseline (169.091 us; speedup 1.0000x reference)
//
#include <hip/hip_runtime.h>
#include <hip/hip_bf16.h>

// Problem constants (match the reference).
#define NG 32768
#define MP 8192
#define BG_VAL (-1.0f)
#define MAX_SCALE 0.02f

// -0.5 * log2(e): folded into the precomputed inverse covariance so the inner
// loop computes alpha = w * exp2(-quad_scaled) with zero extra multiplies.
#define HALF_LOG2E 0.72134752044448170f

#define BLK 256               // threads per block
#define PPT 2                 // points per thread (amortize LDS broadcast reads)
#define PT_PER_BLK (BLK * PPT)        // 512 points per block
#define CHUNK 512             // gaussians per chunk
#define NCHUNK (NG / CHUNK)   // 64
#define PT_TILES (MP / PT_PER_BLK)    // 16

// ---------------------------------------------------------------------------
// Kernel 1: per-gaussian precompute.
// Layout per gaussian: 3x float4:
//   g0 = (ic00*c, ic11*c, ic22*c, 2*ic01*c)
//   g1 = (2*ic02*c, 2*ic12*c, cx, cy)
//   g2 = (cz, w, w*v, 0)
// where c = 0.5*log2(e), so alpha = w * exp2(-(d^T G d)).
// ---------------------------------------------------------------------------
__global__ __launch_bounds__(256) void vegs_precompute(
    const float* __restrict__ xyz,
    const float* __restrict__ weight_raw,
    const float* __restrict__ scaling_raw,
    const float* __restrict__ rotation_raw,
    const float* __restrict__ values_raw,
    float4* __restrict__ gp)
{
    int n = blockIdx.x * blockDim.x + threadIdx.x;
    if (n >= NG) return;

    // s = exp(scaling_raw)
    float s0 = __expf(scaling_raw[n * 3 + 0]);
    float s1 = __expf(scaling_raw[n * 3 + 1]);
    float s2 = __expf(scaling_raw[n * 3 + 2]);

    // soft-clamp norm to MAX_SCALE via tanh
    float r = sqrtf(s0 * s0 + s1 * s1 + s2 * s2) + 1e-8f;
    float rs = MAX_SCALE * tanhf(r * (1.0f / MAX_SCALE));
    float k = rs / r;
    s0 *= k; s1 *= k; s2 *= k;

    float i0 = 1.0f / (s0 * s0);
    float i1 = 1.0f / (s1 * s1);
    float i2 = 1.0f / (s2 * s2);

    // normalized quaternion
    float qw = rotation_raw[n * 4 + 0];
    float qx = rotation_raw[n * 4 + 1];
    float qy = rotation_raw[n * 4 + 2];
    float qz = rotation_raw[n * 4 + 3];
    float qn = sqrtf(qw * qw + qx * qx + qy * qy + qz * qz) + 1e-12f;
    float inv_qn = 1.0f / qn;
    qw *= inv_qn; qx *= inv_qn; qy *= inv_qn; qz *= inv_qn;

    // rotation matrix
    float r00 = 1.0f - 2.0f * (qy * qy + qz * qz);
    float r01 = 2.0f * (qx * qy - qw * qz);
    float r02 = 2.0f * (qx * qz + qw * qy);
    float r10 = 2.0f * (qx * qy + qw * qz);
    float r11 = 1.0f - 2.0f * (qx * qx + qz * qz);
    float r12 = 2.0f * (qy * qz - qw * qx);
    float r20 = 2.0f * (qx * qz - qw * qy);
    float r21 = 2.0f * (qy * qz + qw * qx);
    float r22 = 1.0f - 2.0f * (qx * qx + qy * qy);

    // inv_cov = R diag(1/s^2) R^T  (symmetric)
    float ic00 = r00 * r00 * i0 + r01 * r01 * i1 + r02 * r02 * i2;
    float ic11 = r10 * r10 * i0 + r11 * r11 * i1 + r12 * r12 * i2;
    float ic22 = r20 * r20 * i0 + r21 * r21 * i1 + r22 * r22 * i2;
    float ic01 = r00 * r10 * i0 + r01 * r11 * i1 + r02 * r12 * i2;
    float ic02 = r00 * r20 * i0 + r01 * r21 * i1 + r02 * r22 * i2;
    float ic12 = r10 * r20 * i0 + r11 * r21 * i1 + r12 * r22 * i2;

    float w = 1.0f / (1.0f + __expf(-weight_raw[n]));
    float v = 1.0f / (1.0f + __expf(-values_raw[n]));

    const float c = HALF_LOG2E;
    gp[n * 3 + 0] = make_float4(ic00 * c, ic11 * c, ic22 * c, 2.0f * ic01 * c);
    gp[n * 3 + 1] = make_float4(2.0f * ic02 * c, 2.0f * ic12 * c,
                                xyz[n * 3 + 0], xyz[n * 3 + 1]);
    gp[n * 3 + 2] = make_float4(xyz[n * 3 + 2], w, w * v, 0.0f);
}

// ---------------------------------------------------------------------------
// Kernel 2: main pairwise evaluation.
// grid = (PT_TILES, NCHUNK). Each block: 256 threads x 2 points = 512 points,
// vs one chunk of 512 gaussians staged in LDS (24 KB, uniform broadcast
// reads). Writes (num, den) partials per (chunk, point).
// ---------------------------------------------------------------------------
__global__ __launch_bounds__(BLK) void vegs_main(
    const float* __restrict__ x,
    const float4* __restrict__ gp,
    float2* __restrict__ partial)
{
    __shared__ float4 lds[CHUNK * 3];

    const int m0 = blockIdx.x * PT_PER_BLK + threadIdx.x;  // point A
    const int m1 = m0 + BLK;                               // point B
    const int c  = blockIdx.y;                             // chunk index

    // cooperative stage: 512 gaussians * 3 float4 = 1536 float4
    const float4* __restrict__ src = gp + (size_t)c * CHUNK * 3;
    #pragma unroll
    for (int i = threadIdx.x; i < CHUNK * 3; i += BLK) lds[i] = src[i];

    // point coords (p = (x+1)/2)
    float a0 = (x[m0 * 3 + 0] + 1.0f) * 0.5f;
    float a1 = (x[m0 * 3 + 1] + 1.0f) * 0.5f;
    float a2 = (x[m0 * 3 + 2] + 1.0f) * 0.5f;
    float b0 = (x[m1 * 3 + 0] + 1.0f) * 0.5f;
    float b1 = (x[m1 * 3 + 1] + 1.0f) * 0.5f;
    float b2 = (x[m1 * 3 + 2] + 1.0f) * 0.5f;

    __syncthreads();

    float numA = 0.0f, denA = 0.0f;
    float numB = 0.0f, denB = 0.0f;

    #pragma unroll 4
    for (int j = 0; j < CHUNK; ++j) {
        float4 g0 = lds[j * 3 + 0];
        float4 g1 = lds[j * 3 + 1];
        float4 g2 = lds[j * 3 + 2];

        // point A
        {
            float d0 = a0 - g1.z;
            float d1 = a1 - g1.w;
            float d2 = a2 - g2.x;
            float t0 = fmaf(g0.w, d1, g0.x * d0);
            t0 = fmaf(g1.x, d2, t0);
            float t1 = fmaf(g1.y, d2, g0.y * d1);
            float q = fmaf(d0, t0, fmaf(d1, t1, (g0.z * d2) * d2));
            float e = __builtin_amdgcn_exp2f(-q);
            denA = fmaf(g2.y, e, denA);
            numA = fmaf(g2.z, e, numA);
        }
        // point B
        {
            float d0 = b0 - g1.z;
            float d1 = b1 - g1.w;
            float d2 = b2 - g2.x;
            float t0 = fmaf(g0.w, d1, g0.x * d0);
            t0 = fmaf(g1.x, d2, t0);
            float t1 = fmaf(g1.y, d2, g0.y * d1);
            float q = fmaf(d0, t0, fmaf(d1, t1, (g0.z * d2) * d2));
            float e = __builtin_amdgcn_exp2f(-q);
            denB = fmaf(g2.y, e, denB);
            numB = fmaf(g2.z, e, numB);
        }
    }

    partial[(size_t)c * MP + m0] = make_float2(numA, denA);
    partial[(size_t)c * MP + m1] = make_float2(numB, denB);
}

// ---------------------------------------------------------------------------
// Kernel 3: reduce partials over chunks, apply background select.
// ---------------------------------------------------------------------------
__global__ __launch_bounds__(256) void vegs_reduce(
    const float2* __restrict__ partial,
    float* __restrict__ out)
{
    int m = blockIdx.x * blockDim.x + threadIdx.x;
    if (m >= MP) return;
    float num = 0.0f, den = 0.0f;
    #pragma unroll 8
    for (int c = 0; c < NCHUNK; ++c) {
        float2 p = partial[(size_t)c * MP + m];
        num += p.x;
        den += p.y;
    }
    out[m] = (den > 1e-8f) ? num : BG_VAL;
}

extern "C" void kernel_launch(void* const* d_in, const int* in_sizes, int n_in,
                              void* d_out, int out_size, void* d_ws, size_t ws_size,
                              hipStream_t stream) {
    const float* x            = (const float*)d_in[0];
    const float* xyz          = (const float*)d_in[1];
    const float* weight_raw   = (const float*)d_in[2];
    const float* scaling_raw  = (const float*)d_in[3];
    const float* rotation_raw = (const float*)d_in[4];
    const float* values_raw   = (const float*)d_in[5];
    float* out = (float*)d_out;

    // workspace layout: gp (1.5 MB) then partials (4 MB)
    char* ws = (char*)d_ws;
    float4* gp = (float4*)ws;
    float2* partial = (float2*)(ws + (size_t)NG * 3 * sizeof(float4));

    vegs_precompute<<<NG / 256, 256, 0, stream>>>(
        xyz, weight_raw, scaling_raw, rotation_raw, values_raw, gp);

    dim3 grid(PT_TILES, NCHUNK);
    vegs_main<<<grid, BLK, 0, stream>>>(x, gp, partial);

    vegs_reduce<<<MP / 256, 256, 0, stream>>>(partial, out);
}